// Round 3
// baseline (3903.225 us; speedup 1.0000x reference)
//
#include <hip/hip_runtime.h>

#define NB 2
#define CH 256
#define HS 96
#define HW 9216
#define CHW 2359296      // 256*9216
#define INNER 14
#define NF 252
#define SCALE 0.0625f    // 1/sqrt(256)

// ---------------- 1x1 conv (GEMM): 32 couts/block, 2 pixels/thread ----------
template<int CIN>
__global__ __launch_bounds__(256)
void k_conv1x1(const float* __restrict__ in, const float* __restrict__ w,
               const float* __restrict__ bias, float* __restrict__ out) {
    __shared__ float wsh[CIN][32];
    const int tid = threadIdx.x;
    const int coB = blockIdx.y * 32;
    for (int e = tid; e < CIN * 32; e += 256) {
        int ci = e >> 5, col = e & 31;
        wsh[ci][col] = w[(coB + col) * CIN + ci];
    }
    __syncthreads();
    const int P0  = blockIdx.x * 512 + tid;   // 512-aligned blocks never cross batch
    const int b   = P0 / HW;
    const int pp0 = P0 - b * HW;
    const int pp1 = pp0 + 256;
    const float* inb = in + (size_t)b * CIN * HW;
    float acc0[32], acc1[32];
    #pragma unroll
    for (int j = 0; j < 32; ++j) { acc0[j] = 0.f; acc1[j] = 0.f; }
    for (int ci = 0; ci < CIN; ++ci) {
        float x0 = inb[(size_t)ci * HW + pp0];
        float x1 = inb[(size_t)ci * HW + pp1];
        const float4* wr = (const float4*)wsh[ci];
        #pragma unroll
        for (int q = 0; q < 8; ++q) {
            float4 wv = wr[q];
            acc0[q*4+0] += wv.x*x0; acc0[q*4+1] += wv.y*x0;
            acc0[q*4+2] += wv.z*x0; acc0[q*4+3] += wv.w*x0;
            acc1[q*4+0] += wv.x*x1; acc1[q*4+1] += wv.y*x1;
            acc1[q*4+2] += wv.z*x1; acc1[q*4+3] += wv.w*x1;
        }
    }
    float* ob = out + (size_t)b * CH * HW;
    #pragma unroll
    for (int j = 0; j < 32; ++j) {
        float bv = bias[coB + j];
        ob[(size_t)(coB + j) * HW + pp0] = acc0[j] + bv;
        ob[(size_t)(coB + j) * HW + pp1] = acc1[j] + bv;
    }
}

// ---------------- reduce: 256 -> 14 channels ----------------
__global__ __launch_bounds__(64)
void k_reduce(const float* __restrict__ fmap, const float* __restrict__ w,
              const float* __restrict__ bias, float* __restrict__ xr) {
    __shared__ float wsh[256][16];
    const int tid = threadIdx.x;
    for (int e = tid; e < 256 * 16; e += 64) {
        int ci = e >> 4, co = e & 15;
        wsh[ci][co] = (co < INNER) ? w[co * 256 + ci] : 0.f;
    }
    __syncthreads();
    const int P  = blockIdx.x * 64 + tid;
    const int b  = P / HW;
    const int pp = P - b * HW;
    const float* fb = fmap + (size_t)b * CHW;
    float acc[16];
    #pragma unroll
    for (int j = 0; j < 16; ++j) acc[j] = 0.f;
    for (int ci = 0; ci < 256; ++ci) {
        float xv = fb[(size_t)ci * HW + pp];
        const float4* wr = (const float4*)wsh[ci];
        #pragma unroll
        for (int q = 0; q < 4; ++q) {
            float4 wv = wr[q];
            acc[q*4+0] += wv.x*xv; acc[q*4+1] += wv.y*xv;
            acc[q*4+2] += wv.z*xv; acc[q*4+3] += wv.w*xv;
        }
    }
    float* xb = xr + (size_t)b * INNER * HW;
    #pragma unroll
    for (int co = 0; co < INNER; ++co)
        xb[(size_t)co * HW + pp] = acc[co] + bias[co];
}

// ------- dilated 3x3 conv + 6 spatial-transform products -> feats (252 ch) ----
__global__ __launch_bounds__(256)
void k_dil(const float* __restrict__ xr, const float* __restrict__ dw,
           const float* __restrict__ db, float* __restrict__ feats) {
    int bid = blockIdx.x;
    const int hb = bid % 36; bid /= 36;
    const int oc = bid % 14; bid /= 14;
    const int b  = bid & 1;  bid >>= 1;
    const int d  = bid;              // 0..2
    const int dil = d + 1;
    __shared__ float wsh[126];
    const int tid = threadIdx.x;
    if (tid < 126) wsh[tid] = dw[(d * 14 + oc) * 126 + tid];
    __syncthreads();
    const int p = hb * 256 + tid;
    const int h = p / 96, w = p - (p / 96) * 96;
    const float* xb = xr + (size_t)b * INNER * HW;
    float acc = db[d * 14 + oc];
    for (int ic = 0; ic < 14; ++ic) {
        const float* xc = xb + (size_t)ic * HW;
        #pragma unroll
        for (int kh = 0; kh < 3; ++kh) {
            int ih = h + (kh - 1) * dil;
            if (ih < 0 || ih >= 96) continue;
            #pragma unroll
            for (int kw = 0; kw < 3; ++kw) {
                int iw = w + (kw - 1) * dil;
                if (iw < 0 || iw >= 96) continue;
                acc += xc[ih * 96 + iw] * wsh[ic * 9 + kh * 3 + kw];
            }
        }
    }
    // transforms of xr channel oc at this pixel
    const float* xo = xb + (size_t)oc * HW;
    const int H1 = 95;
    float t0 = xo[h * 96 + w];
    float t1 = xo[h * 96 + (H1 - w)];          // flip w
    float t2 = xo[(H1 - h) * 96 + w];          // flip h
    float t3 = xo[w * 96 + (H1 - h)];          // rot90
    float t4 = xo[(H1 - h) * 96 + (H1 - w)];   // rot180
    float t5 = xo[(H1 - w) * 96 + h];          // rot270
    float* fo = feats + (size_t)b * NF * HW;
    const int ch0 = d * 6 * 14 + oc;
    fo[(size_t)(ch0 + 0 * 14) * HW + p] = acc * t0;
    fo[(size_t)(ch0 + 1 * 14) * HW + p] = acc * t1;
    fo[(size_t)(ch0 + 2 * 14) * HW + p] = acc * t2;
    fo[(size_t)(ch0 + 3 * 14) * HW + p] = acc * t3;
    fo[(size_t)(ch0 + 4 * 14) * HW + p] = acc * t4;
    fo[(size_t)(ch0 + 5 * 14) * HW + p] = acc * t5;
}

// ---------------- flash attention (fp32) + residual ----------------
// 256 blocks (1/CU), 384 threads, 72 queries/block, K-tile 64, K==V==tok.
#define QT 72
#define KT 64
#define ET 384

__global__ __launch_bounds__(384)
void k_attn(const float* __restrict__ tok, const float* __restrict__ fmap,
            float* __restrict__ outp) {
    __shared__ float Qsh[QT][260];   // 74,880 B (rows 16B aligned, stride%32==4)
    __shared__ float KV[KT][260];    // 66,560 B
    __shared__ float Psh[KT][76];    // 19,456 B  (72 query cols + pad)
    const int tid = threadIdx.x;
    const int ti = tid >> 4;         // 0..23 -> 3 queries each
    const int tj = tid & 15;         // key group
    const int b  = blockIdx.x >> 7;
    const int q0 = (blockIdx.x & 127) * QT;
    const float* tb = tok + (size_t)b * CHW;

    for (int e = tid; e < QT * CH; e += ET) {
        int i = e % QT, c = e / QT;
        Qsh[i][c] = tb[(size_t)c * HW + q0 + i] * SCALE;
    }
    const int i0 = ti * 3;
    float mm[3], ll[3], acc[3][16];
    #pragma unroll
    for (int ii = 0; ii < 3; ++ii) {
        mm[ii] = -1e30f; ll[ii] = 0.f;
        #pragma unroll
        for (int k = 0; k < 16; ++k) acc[ii][k] = 0.f;
    }

    for (int t = 0; t < HW / KT; ++t) {
        const int k0 = t * KT;
        __syncthreads();                       // KV/Psh safe to overwrite
        for (int e = tid; e < KT * CH; e += ET) {
            int j = e & 63, c = e >> 6;
            KV[j][c] = tb[(size_t)c * HW + k0 + j];
        }
        __syncthreads();
        // ---- scores: 3 queries x 4 keys per thread ----
        float s[3][4];
        #pragma unroll
        for (int ii = 0; ii < 3; ++ii)
            #pragma unroll
            for (int jj = 0; jj < 4; ++jj) s[ii][jj] = 0.f;
        for (int c = 0; c < CH; c += 4) {
            float4 qa = *(const float4*)&Qsh[i0 + 0][c];
            float4 qb = *(const float4*)&Qsh[i0 + 1][c];
            float4 qc = *(const float4*)&Qsh[i0 + 2][c];
            #pragma unroll
            for (int jj = 0; jj < 4; ++jj) {
                float4 kv = *(const float4*)&KV[tj + 16 * jj][c];
                s[0][jj] += qa.x*kv.x + qa.y*kv.y + qa.z*kv.z + qa.w*kv.w;
                s[1][jj] += qb.x*kv.x + qb.y*kv.y + qb.z*kv.z + qb.w*kv.w;
                s[2][jj] += qc.x*kv.x + qc.y*kv.y + qc.z*kv.z + qc.w*kv.w;
            }
        }
        // ---- online softmax update ----
        #pragma unroll
        for (int ii = 0; ii < 3; ++ii) {
            float tm = fmaxf(fmaxf(s[ii][0], s[ii][1]), fmaxf(s[ii][2], s[ii][3]));
            #pragma unroll
            for (int msk = 1; msk < 16; msk <<= 1)
                tm = fmaxf(tm, __shfl_xor(tm, msk, 64));
            float mn = fmaxf(mm[ii], tm);
            float alpha = __expf(mm[ii] - mn);
            mm[ii] = mn;
            float ps = 0.f;
            #pragma unroll
            for (int jj = 0; jj < 4; ++jj) {
                float pv = __expf(s[ii][jj] - mn);
                s[ii][jj] = pv;
                ps += pv;
            }
            #pragma unroll
            for (int msk = 1; msk < 16; msk <<= 1)
                ps += __shfl_xor(ps, msk, 64);
            ll[ii] = ll[ii] * alpha + ps;
            #pragma unroll
            for (int k = 0; k < 16; ++k) acc[ii][k] *= alpha;
            #pragma unroll
            for (int jj = 0; jj < 4; ++jj)
                Psh[tj + 16 * jj][i0 + ii] = s[ii][jj];
        }
        __syncthreads();
        // ---- PV: each thread owns 3 queries x 16 interleaved channels ----
        for (int j = 0; j < KT; ++j) {
            float p0 = Psh[j][i0 + 0], p1 = Psh[j][i0 + 1], p2 = Psh[j][i0 + 2];
            #pragma unroll
            for (int k = 0; k < 4; ++k) {
                float4 v = *(const float4*)&KV[j][tj * 4 + k * 64];
                acc[0][k*4+0] += p0*v.x; acc[0][k*4+1] += p0*v.y;
                acc[0][k*4+2] += p0*v.z; acc[0][k*4+3] += p0*v.w;
                acc[1][k*4+0] += p1*v.x; acc[1][k*4+1] += p1*v.y;
                acc[1][k*4+2] += p1*v.z; acc[1][k*4+3] += p1*v.w;
                acc[2][k*4+0] += p2*v.x; acc[2][k*4+1] += p2*v.y;
                acc[2][k*4+2] += p2*v.z; acc[2][k*4+3] += p2*v.w;
            }
        }
    }
    // ---- epilogue: normalize, stage to LDS (reuse Qsh), coalesced write ----
    __syncthreads();
    float* Osh = (float*)Qsh;        // [256][73] = 18,688 floats <= 18,720
    #pragma unroll
    for (int ii = 0; ii < 3; ++ii) {
        float inv = 1.f / ll[ii];
        #pragma unroll
        for (int k = 0; k < 4; ++k)
            #pragma unroll
            for (int m = 0; m < 4; ++m) {
                int c = tj * 4 + k * 64 + m;
                Osh[c * 73 + i0 + ii] = acc[ii][k*4+m] * inv;
            }
    }
    __syncthreads();
    const float* fb = fmap + (size_t)b * CHW;
    float* ob = outp + (size_t)b * CHW;
    for (int e = tid; e < QT * CH; e += ET) {
        int i = e % QT, c = e / QT;
        size_t g = (size_t)c * HW + q0 + i;
        ob[g] = fb[g] + 0.2f * Osh[c * 73 + i];
    }
}

extern "C" void kernel_launch(void* const* d_in, const int* in_sizes, int n_in,
                              void* d_out, int out_size, void* d_ws, size_t ws_size,
                              hipStream_t stream) {
    const float* x        = (const float*)d_in[0];
    const float* proj_w   = (const float*)d_in[1];
    const float* proj_b   = (const float*)d_in[2];
    const float* reduce_w = (const float*)d_in[3];
    const float* reduce_b = (const float*)d_in[4];
    const float* dil_w    = (const float*)d_in[5];
    const float* dil_b    = (const float*)d_in[6];
    const float* fuse_w   = (const float*)d_in[7];
    const float* fuse_b   = (const float*)d_in[8];
    float* out = (float*)d_out;

    float* ws    = (float*)d_ws;
    float* fmap  = ws;                    // 4,718,592 f
    float* xr    = fmap + 4718592;        //   258,048 f
    float* feats = xr + 258048;           // 4,644,864 f
    float* tok   = feats + 4644864;       // 4,718,592 f  (fused output)

    k_conv1x1<256><<<dim3(36, 8), 256, 0, stream>>>(x, proj_w, proj_b, fmap);
    k_reduce<<<288, 64, 0, stream>>>(fmap, reduce_w, reduce_b, xr);
    k_dil<<<3024, 256, 0, stream>>>(xr, dil_w, dil_b, feats);
    k_conv1x1<252><<<dim3(36, 8), 256, 0, stream>>>(feats, fuse_w, fuse_b, tok);
    k_attn<<<256, 384, 0, stream>>>(tok, fmap, out);
}

// Round 5
// 871.746 us; speedup vs baseline: 4.4775x; 4.4775x over previous
//
#include <hip/hip_runtime.h>
#include <hip/hip_bf16.h>

#define NB 2
#define CH 256
#define HS 96
#define HW 9216
#define CHW 2359296      // 256*9216
#define INNER 14
#define NF 252
#define SCALE 0.0625f    // 1/sqrt(256)

using f32x4 = __attribute__((ext_vector_type(4))) float;
using s16x8 = __attribute__((ext_vector_type(8))) short;

// ---------------- 1x1 conv (GEMM): 32 couts/block, 2 pixels/thread ----------
template<int CIN, typename OT>
__global__ __launch_bounds__(256)
void k_conv1x1(const float* __restrict__ in, const float* __restrict__ w,
               const float* __restrict__ bias, OT* __restrict__ out) {
    __shared__ float wsh[CIN][32];
    const int tid = threadIdx.x;
    const int coB = blockIdx.y * 32;
    for (int e = tid; e < CIN * 32; e += 256) {
        int ci = e >> 5, col = e & 31;
        wsh[ci][col] = w[(coB + col) * CIN + ci];
    }
    __syncthreads();
    const int P0  = blockIdx.x * 512 + tid;
    const int b   = P0 / HW;
    const int pp0 = P0 - b * HW;
    const int pp1 = pp0 + 256;
    const float* inb = in + (size_t)b * CIN * HW;
    float acc0[32], acc1[32];
    #pragma unroll
    for (int j = 0; j < 32; ++j) { acc0[j] = 0.f; acc1[j] = 0.f; }
    for (int ci = 0; ci < CIN; ++ci) {
        float x0 = inb[(size_t)ci * HW + pp0];
        float x1 = inb[(size_t)ci * HW + pp1];
        const float4* wr = (const float4*)wsh[ci];
        #pragma unroll
        for (int q = 0; q < 8; ++q) {
            float4 wv = wr[q];
            acc0[q*4+0] += wv.x*x0; acc0[q*4+1] += wv.y*x0;
            acc0[q*4+2] += wv.z*x0; acc0[q*4+3] += wv.w*x0;
            acc1[q*4+0] += wv.x*x1; acc1[q*4+1] += wv.y*x1;
            acc1[q*4+2] += wv.z*x1; acc1[q*4+3] += wv.w*x1;
        }
    }
    OT* ob = out + (size_t)b * CH * HW;
    #pragma unroll
    for (int j = 0; j < 32; ++j) {
        float bv = bias[coB + j];
        ob[(size_t)(coB + j) * HW + pp0] = (OT)(acc0[j] + bv);
        ob[(size_t)(coB + j) * HW + pp1] = (OT)(acc1[j] + bv);
    }
}

// ---------------- reduce: 256 -> 14 channels ----------------
__global__ __launch_bounds__(64)
void k_reduce(const float* __restrict__ fmap, const float* __restrict__ w,
              const float* __restrict__ bias, float* __restrict__ xr) {
    __shared__ float wsh[256][16];
    const int tid = threadIdx.x;
    for (int e = tid; e < 256 * 16; e += 64) {
        int ci = e >> 4, co = e & 15;
        wsh[ci][co] = (co < INNER) ? w[co * 256 + ci] : 0.f;
    }
    __syncthreads();
    const int P  = blockIdx.x * 64 + tid;
    const int b  = P / HW;
    const int pp = P - b * HW;
    const float* fb = fmap + (size_t)b * CHW;
    float acc[16];
    #pragma unroll
    for (int j = 0; j < 16; ++j) acc[j] = 0.f;
    for (int ci = 0; ci < 256; ++ci) {
        float xv = fb[(size_t)ci * HW + pp];
        const float4* wr = (const float4*)wsh[ci];
        #pragma unroll
        for (int q = 0; q < 4; ++q) {
            float4 wv = wr[q];
            acc[q*4+0] += wv.x*xv; acc[q*4+1] += wv.y*xv;
            acc[q*4+2] += wv.z*xv; acc[q*4+3] += wv.w*xv;
        }
    }
    float* xb = xr + (size_t)b * INNER * HW;
    #pragma unroll
    for (int co = 0; co < INNER; ++co)
        xb[(size_t)co * HW + pp] = acc[co] + bias[co];
}

// ------- dilated 3x3 conv + 6 spatial-transform products -> feats (252 ch) ----
__global__ __launch_bounds__(256)
void k_dil(const float* __restrict__ xr, const float* __restrict__ dw,
           const float* __restrict__ db, float* __restrict__ feats) {
    int bid = blockIdx.x;
    const int hb = bid % 36; bid /= 36;
    const int oc = bid % 14; bid /= 14;
    const int b  = bid & 1;  bid >>= 1;
    const int d  = bid;              // 0..2
    const int dil = d + 1;
    __shared__ float wsh[126];
    const int tid = threadIdx.x;
    if (tid < 126) wsh[tid] = dw[(d * 14 + oc) * 126 + tid];
    __syncthreads();
    const int p = hb * 256 + tid;
    const int h = p / 96, w = p - (p / 96) * 96;
    const float* xb = xr + (size_t)b * INNER * HW;
    float acc = db[d * 14 + oc];
    for (int ic = 0; ic < 14; ++ic) {
        const float* xc = xb + (size_t)ic * HW;
        #pragma unroll
        for (int kh = 0; kh < 3; ++kh) {
            int ih = h + (kh - 1) * dil;
            if (ih < 0 || ih >= 96) continue;
            #pragma unroll
            for (int kw = 0; kw < 3; ++kw) {
                int iw = w + (kw - 1) * dil;
                if (iw < 0 || iw >= 96) continue;
                acc += xc[ih * 96 + iw] * wsh[ic * 9 + kh * 3 + kw];
            }
        }
    }
    const float* xo = xb + (size_t)oc * HW;
    const int H1 = 95;
    float t0 = xo[h * 96 + w];
    float t1 = xo[h * 96 + (H1 - w)];
    float t2 = xo[(H1 - h) * 96 + w];
    float t3 = xo[w * 96 + (H1 - h)];
    float t4 = xo[(H1 - h) * 96 + (H1 - w)];
    float t5 = xo[(H1 - w) * 96 + h];
    float* fo = feats + (size_t)b * NF * HW;
    const int ch0 = d * 6 * 14 + oc;
    fo[(size_t)(ch0 + 0 * 14) * HW + p] = acc * t0;
    fo[(size_t)(ch0 + 1 * 14) * HW + p] = acc * t1;
    fo[(size_t)(ch0 + 2 * 14) * HW + p] = acc * t2;
    fo[(size_t)(ch0 + 3 * 14) * HW + p] = acc * t3;
    fo[(size_t)(ch0 + 4 * 14) * HW + p] = acc * t4;
    fo[(size_t)(ch0 + 5 * 14) * HW + p] = acc * t5;
}

// ------- transpose: tok_c bf16 [C][HW] -> tok_t bf16 [HW][C] -------
__global__ __launch_bounds__(256)
void k_tr(const unsigned short* __restrict__ tc, unsigned short* __restrict__ tt) {
    const int tid = threadIdx.x;
    int bid = blockIdx.x;
    const int b = bid / 576;
    const int r = bid - b * 576;          // 0..575
    const int t0 = (r >> 2) * 64;
    const int c0 = (r & 3) * 64;
    __shared__ unsigned int T[64][37];
    const unsigned short* tcb = tc + (size_t)b * CHW;
    unsigned short* ttb = tt + (size_t)b * CHW;
    for (int e = tid; e < 2048; e += 256) {
        int to = e & 63, chp = e >> 6;    // chp 0..31 (pair of channels)
        unsigned int v0 = tcb[(size_t)(c0 + 2*chp)     * HW + t0 + to];
        unsigned int v1 = tcb[(size_t)(c0 + 2*chp + 1) * HW + t0 + to];
        T[to][chp] = (v1 << 16) | v0;
    }
    __syncthreads();
    for (int e = tid; e < 2048; e += 256) {
        int to = e >> 5, chp = e & 31;
        ((unsigned int*)(ttb + (size_t)(t0 + to) * CH + c0))[chp] = T[to][chp];
    }
}

// ---------------- bf16 MFMA flash attention + residual ----------------
// 288 blocks, 256 thr (4 waves x 16 q), KV tile 64 keys, D=256.
#define KTILE 64
#define NKT 144

__device__ __forceinline__ unsigned int pk_bf16(float lo, float hi) {
    unsigned int l = __bfloat16_as_ushort(__float2bfloat16(lo));
    unsigned int h = __bfloat16_as_ushort(__float2bfloat16(hi));
    return (h << 16) | l;
}

__global__ __launch_bounds__(256, 2)
void k_attn2(const unsigned short* __restrict__ tok_t,
             const unsigned short* __restrict__ tok_c,
             const float* __restrict__ fmap, float* __restrict__ outp) {
    __shared__ unsigned short Kt[64][256];   // [key][ch ^ ((key&7)<<3)]
    __shared__ unsigned short Vt[256][64];   // [ch][key ^ ((ch&7)<<3)]
    __shared__ unsigned short Psh[4][16][72];// per-wave [q][key], 16B-mult rows
    const int tid  = threadIdx.x;
    const int wid  = tid >> 6;
    const int lane = tid & 63;
    const int lq   = lane & 15;
    const int lg   = lane >> 4;

    // XCD-grouped remap: dispatch i -> XCD i&7 gets contiguous q-range
    const int blk = blockIdx.x;
    const int qb  = (blk & 7) * 36 + (blk >> 3);   // 0..287
    const int b   = qb / 144;
    const int q0  = (qb - b * 144) * 64;
    const unsigned short* tt = tok_t + (size_t)b * CHW;
    const unsigned short* tc = tok_c + (size_t)b * CHW;

    // Q fragments (B-operand of S^T): col=q=lq, k = ks*32 + 8*lg + j
    s16x8 qf[8];
    {
        const unsigned short* qrow = tt + (size_t)(q0 + wid*16 + lq) * CH + 8*lg;
        #pragma unroll
        for (int ks = 0; ks < 8; ++ks)
            qf[ks] = *(const s16x8*)(qrow + 32*ks);
    }
    float m_r = -1e30f, l_r = 0.f;
    f32x4 oacc[16];
    #pragma unroll
    for (int ct = 0; ct < 16; ++ct) oacc[ct] = (f32x4){0.f,0.f,0.f,0.f};

    for (int t = 0; t < NKT; ++t) {
        const int k0 = t * KTILE;
        __syncthreads();
        // stage Kt (from token-major)
        for (int c = tid; c < 2048; c += 256) {
            int key = c >> 5, cho = (c & 31) * 8;
            s16x8 v = *(const s16x8*)(tt + (size_t)(k0 + key) * CH + cho);
            *(s16x8*)(&Kt[key][cho ^ ((key & 7) << 3)]) = v;
        }
        // stage Vt (from channel-major)
        for (int c = tid; c < 2048; c += 256) {
            int ch = c >> 3, ko = (c & 7) * 8;
            s16x8 v = *(const s16x8*)(tc + (size_t)ch * HW + k0 + ko);
            *(s16x8*)(&Vt[ch][ko ^ ((ch & 7) << 3)]) = v;
        }
        __syncthreads();

        // ---- S^T = K·Q^T : 4 key-subtiles ----
        float s[16];
        #pragma unroll
        for (int mt = 0; mt < 4; ++mt) {
            f32x4 acc = (f32x4){0.f,0.f,0.f,0.f};
            const int key = mt * 16 + lq;
            const int sw  = (key & 7) << 3;
            #pragma unroll
            for (int ks = 0; ks < 8; ++ks) {
                s16x8 af = *(const s16x8*)(&Kt[key][(ks*32 + 8*lg) ^ sw]);
                acc = __builtin_amdgcn_mfma_f32_16x16x32_bf16(af, qf[ks], acc, 0, 0, 0);
            }
            #pragma unroll
            for (int r = 0; r < 4; ++r) s[mt*4 + r] = acc[r] * SCALE;
        }
        // ---- online softmax (per q = lq; keys spread over regs+groups) ----
        float tm = s[0];
        #pragma unroll
        for (int i = 1; i < 16; ++i) tm = fmaxf(tm, s[i]);
        tm = fmaxf(tm, __shfl_xor(tm, 16));
        tm = fmaxf(tm, __shfl_xor(tm, 32));
        const float mn = fmaxf(m_r, tm);
        const float alpha = __expf(m_r - mn);
        m_r = mn;
        float ps = 0.f;
        #pragma unroll
        for (int i = 0; i < 16; ++i) { s[i] = __expf(s[i] - mn); ps += s[i]; }
        ps += __shfl_xor(ps, 16);
        ps += __shfl_xor(ps, 32);
        l_r = l_r * alpha + ps;
        #pragma unroll
        for (int ct = 0; ct < 16; ++ct) {
            oacc[ct][0] *= alpha; oacc[ct][1] *= alpha;
            oacc[ct][2] *= alpha; oacc[ct][3] *= alpha;
        }
        // ---- P -> per-wave LDS (keys 16*kt + 4*lg + r at row q=lq) ----
        #pragma unroll
        for (int kt = 0; kt < 4; ++kt) {
            *(unsigned int*)&Psh[wid][lq][16*kt + 4*lg]     = pk_bf16(s[kt*4+0], s[kt*4+1]);
            *(unsigned int*)&Psh[wid][lq][16*kt + 4*lg + 2] = pk_bf16(s[kt*4+2], s[kt*4+3]);
        }
        // B-frags for PV: lane reads its own wave's row q=lq, keys 8*lg..+7
        s16x8 pb0 = *(const s16x8*)&Psh[wid][lq][8*lg];
        s16x8 pb1 = *(const s16x8*)&Psh[wid][lq][32 + 8*lg];
        // ---- PV: out^T[ch][q], A = V^T frags from Vt ----
        #pragma unroll
        for (int ct = 0; ct < 16; ++ct) {
            const int ch = ct * 16 + lq;
            const int sw = (ch & 7) << 3;
            s16x8 va0 = *(const s16x8*)(&Vt[ch][(8*lg) ^ sw]);
            s16x8 va1 = *(const s16x8*)(&Vt[ch][(32 + 8*lg) ^ sw]);
            oacc[ct] = __builtin_amdgcn_mfma_f32_16x16x32_bf16(va0, pb0, oacc[ct], 0, 0, 0);
            oacc[ct] = __builtin_amdgcn_mfma_f32_16x16x32_bf16(va1, pb1, oacc[ct], 0, 0, 0);
        }
    }
    // ---- epilogue: normalize + residual, direct write ----
    const float linv = 1.f / l_r;
    const float* fb = fmap + (size_t)b * CHW;
    float* ob = outp + (size_t)b * CHW;
    const int qg = q0 + wid * 16 + lq;
    #pragma unroll
    for (int ct = 0; ct < 16; ++ct)
        #pragma unroll
        for (int cr = 0; cr < 4; ++cr) {
            const int ch = ct * 16 + 4 * lg + cr;
            const size_t g = (size_t)ch * HW + qg;
            ob[g] = fb[g] + 0.2f * (oacc[ct][cr] * linv);
        }
}

extern "C" void kernel_launch(void* const* d_in, const int* in_sizes, int n_in,
                              void* d_out, int out_size, void* d_ws, size_t ws_size,
                              hipStream_t stream) {
    const float* x        = (const float*)d_in[0];
    const float* proj_w   = (const float*)d_in[1];
    const float* proj_b   = (const float*)d_in[2];
    const float* reduce_w = (const float*)d_in[3];
    const float* reduce_b = (const float*)d_in[4];
    const float* dil_w    = (const float*)d_in[5];
    const float* dil_b    = (const float*)d_in[6];
    const float* fuse_w   = (const float*)d_in[7];
    const float* fuse_b   = (const float*)d_in[8];
    float* out = (float*)d_out;

    float* ws    = (float*)d_ws;
    float* fmap  = ws;                           // 4,718,592 f
    float* xr    = fmap + 4718592;               //   258,048 f
    float* feats = xr + 258048;                  // 4,644,864 f
    unsigned short* tok_c = (unsigned short*)(feats + 4644864);   // 4,718,592 u16
    unsigned short* tok_t = tok_c + 4718592;                      // 4,718,592 u16

    k_conv1x1<256, float><<<dim3(36, 8), 256, 0, stream>>>(x, proj_w, proj_b, fmap);
    k_reduce<<<288, 64, 0, stream>>>(fmap, reduce_w, reduce_b, xr);
    k_dil<<<3024, 256, 0, stream>>>(xr, dil_w, dil_b, feats);
    k_conv1x1<252, __hip_bfloat16><<<dim3(36, 8), 256, 0, stream>>>(
        feats, fuse_w, fuse_b, (__hip_bfloat16*)tok_c);
    k_tr<<<1152, 256, 0, stream>>>(tok_c, tok_t);
    k_attn2<<<288, 256, 0, stream>>>(tok_t, tok_c, fmap, out);
}